// Round 1
// baseline (172.377 us; speedup 1.0000x reference)
//
#include <hip/hip_runtime.h>
#include <hip/hip_bf16.h>
#include <cstdint>

typedef __bf16 bf16x8 __attribute__((ext_vector_type(8)));
typedef __bf16 bf16x4 __attribute__((ext_vector_type(4)));
typedef float  f32x4  __attribute__((ext_vector_type(4)));

constexpr int B_N  = 4;
constexpr int C_N  = 256;
constexpr int H_N  = 64;
constexpr int W_N  = 64;
constexpr int CO_N = 256;
constexpr int KT   = 9;              // 3x3 taps
constexpr int RTOT = C_N * KT;       // 2304 reduction length (r = c*9 + k)
constexpr int RC   = 32;             // r-chunk per step
constexpr int NSTEP = RTOT / RC;     // 72
constexpr int APAD = 40;             // LDS row stride (bf16) for A tile (16B-aligned rows)
constexpr int BPAD = 40;             // LDS row stride (u16)  for B tile

// ---- one-time fp32 -> bf16 weight conversion into workspace ----
__global__ void weight_to_bf16(const float* __restrict__ w, __bf16* __restrict__ wb) {
    int i = (blockIdx.x * 256 + threadIdx.x) * 4;
    float4 v = *reinterpret_cast<const float4*>(w + i);
    bf16x4 o;
    o[0] = (__bf16)v.x; o[1] = (__bf16)v.y; o[2] = (__bf16)v.z; o[3] = (__bf16)v.w;
    *reinterpret_cast<bf16x4*>(wb + i) = o;
}

// Fused deformable-conv implicit GEMM.
// Block = one (b, ho) row: 64 output positions (wo) x 256 output channels.
// 512 threads = 8 waves; wave w computes the 64(M) x 32(N) slab at n0 = w*32.
template<bool WS>
__global__ __launch_bounds__(512, 2)
void deform_gemm(const float* __restrict__ x, const float* __restrict__ off,
                 const float* __restrict__ wf, const __bf16* __restrict__ wb,
                 float* __restrict__ out) {
    __shared__ float4 s_w[64 * KT];          // bilinear weights (validity folded in)
    __shared__ int4   s_a[64 * KT];          // 4 clipped corner offsets within a channel plane
    __shared__ __bf16 sA[64][APAD];          // A tile: [wo][rr]
    __shared__ unsigned short sB[256][BPAD]; // B tile: [co][rr] (bf16 bits)

    const int tid  = threadIdx.x;
    const int lane = tid & 63;
    const int wv   = tid >> 6;               // wave id 0..7
    const int bid  = blockIdx.x;
    const int b    = bid >> 6;
    const int ho   = bid & 63;

    // ---- per-(wo, k) bilinear metadata (once per block) ----
    for (int i = tid; i < 64 * KT; i += 512) {
        int p  = i / KT, k = i - p * KT;     // p = wo
        int kh = k / 3,  kw = k - kh * 3;
        float dy = off[(((b * 18) + 2 * k    ) * 64 + ho) * 64 + p];
        float dx = off[(((b * 18) + 2 * k + 1) * 64 + ho) * 64 + p];
        float sy = (float)(ho - 1 + kh) + dy;
        float sx = (float)(p  - 1 + kw) + dx;
        float y0f = floorf(sy), x0f = floorf(sx);
        float fy = sy - y0f,  fx = sx - x0f;
        int y0 = (int)y0f, x0 = (int)x0f;
        int y1 = y0 + 1,   x1 = x0 + 1;
        bool vy0 = (y0 >= 0) & (y0 < H_N), vy1 = (y1 >= 0) & (y1 < H_N);
        bool vx0 = (x0 >= 0) & (x0 < W_N), vx1 = (x1 >= 0) & (x1 < W_N);
        int y0c = min(max(y0, 0), H_N - 1), y1c = min(max(y1, 0), H_N - 1);
        int x0c = min(max(x0, 0), W_N - 1), x1c = min(max(x1, 0), W_N - 1);
        float4 wt;
        wt.x = (1.f - fy) * (1.f - fx) * ((vy0 & vx0) ? 1.f : 0.f);
        wt.y = (1.f - fy) * fx         * ((vy0 & vx1) ? 1.f : 0.f);
        wt.z = fy * (1.f - fx)         * ((vy1 & vx0) ? 1.f : 0.f);
        wt.w = fy * fx                 * ((vy1 & vx1) ? 1.f : 0.f);
        s_w[i] = wt;
        s_a[i] = make_int4(y0c * W_N + x0c, y0c * W_N + x1c,
                           y1c * W_N + x0c, y1c * W_N + x1c);
    }

    f32x4 acc[4][2];
    #pragma unroll
    for (int mf = 0; mf < 4; ++mf)
        #pragma unroll
        for (int nf = 0; nf < 2; ++nf)
            acc[mf][nf] = (f32x4){0.f, 0.f, 0.f, 0.f};

    const float* xb_base = x + (size_t)b * C_N * H_N * W_N;
    const int p_gen = tid & 63;   // which wo this thread generates A values for
    const int rq    = tid >> 6;   // which quarter of the r-chunk
    const int fr    = lane & 15;
    const int fq    = lane >> 4;

    for (int step = 0; step < NSTEP; ++step) {
        const int r0 = step * RC;
        __syncthreads();   // prev MFMA reads done (and meta ready at step 0)

        // ---- A tile: bilinear-sample 64 x 32 cols values ----
        #pragma unroll
        for (int j = 0; j < 4; ++j) {
            int rr = rq * 4 + j;
            int r  = r0 + rr;
            int c  = r / 9;
            int k  = r - c * 9;
            float4 wt = s_w[p_gen * KT + k];
            int4   ad = s_a[p_gen * KT + k];
            const float* xb = xb_base + c * (H_N * W_N);
            float val = wt.x * xb[ad.x] + wt.y * xb[ad.y]
                      + wt.z * xb[ad.z] + wt.w * xb[ad.w];
            sA[p_gen][rr] = (__bf16)val;
        }

        // ---- B tile: weight [256 co][32 r] ----
        {
            int n   = tid >> 1;
            int h16 = (tid & 1) * 16;
            if (WS) {
                const uint4* src = reinterpret_cast<const uint4*>(wb + (size_t)n * RTOT + r0 + h16);
                uint4 v0 = src[0], v1 = src[1];
                *reinterpret_cast<uint4*>(&sB[n][h16])     = v0;
                *reinterpret_cast<uint4*>(&sB[n][h16 + 8]) = v1;
            } else {
                const float4* src = reinterpret_cast<const float4*>(wf + (size_t)n * RTOT + r0 + h16);
                union { __bf16 h[16]; uint4 q[2]; } u;
                #pragma unroll
                for (int i4 = 0; i4 < 4; ++i4) {
                    float4 f = src[i4];
                    u.h[4 * i4 + 0] = (__bf16)f.x; u.h[4 * i4 + 1] = (__bf16)f.y;
                    u.h[4 * i4 + 2] = (__bf16)f.z; u.h[4 * i4 + 3] = (__bf16)f.w;
                }
                *reinterpret_cast<uint4*>(&sB[n][h16])     = u.q[0];
                *reinterpret_cast<uint4*>(&sB[n][h16 + 8]) = u.q[1];
            }
        }
        __syncthreads();

        // ---- MFMA: wave slab 64(M) x 32(N), K=32 ----
        bf16x8 af[4], bfr[2];
        #pragma unroll
        for (int mf = 0; mf < 4; ++mf)
            af[mf] = *reinterpret_cast<const bf16x8*>(&sA[mf * 16 + fr][fq * 8]);
        #pragma unroll
        for (int nf = 0; nf < 2; ++nf)
            bfr[nf] = *reinterpret_cast<const bf16x8*>(&sB[wv * 32 + nf * 16 + fr][fq * 8]);
        #pragma unroll
        for (int mf = 0; mf < 4; ++mf)
            #pragma unroll
            for (int nf = 0; nf < 2; ++nf)
                acc[mf][nf] = __builtin_amdgcn_mfma_f32_16x16x32_bf16(af[mf], bfr[nf], acc[mf][nf], 0, 0, 0);
    }

    // ---- epilogue: D[m][n] -> out[b][n][ho][m] ----
    #pragma unroll
    for (int mf = 0; mf < 4; ++mf)
        #pragma unroll
        for (int nf = 0; nf < 2; ++nf) {
            int n = wv * 32 + nf * 16 + fr;
            #pragma unroll
            for (int j = 0; j < 4; ++j) {
                int m = mf * 16 + fq * 4 + j;
                out[(((size_t)b * CO_N + n) * 64 + ho) * 64 + m] = acc[mf][nf][j];
            }
        }
}

extern "C" void kernel_launch(void* const* d_in, const int* in_sizes, int n_in,
                              void* d_out, int out_size, void* d_ws, size_t ws_size,
                              hipStream_t stream) {
    const float* x   = (const float*)d_in[0];
    const float* off = (const float*)d_in[1];
    const float* w   = (const float*)d_in[2];
    float* out = (float*)d_out;

    const size_t wb_bytes = (size_t)CO_N * RTOT * sizeof(__bf16); // 1.18 MB
    if (ws_size >= wb_bytes) {
        __bf16* wbp = (__bf16*)d_ws;
        weight_to_bf16<<<dim3((CO_N * RTOT) / 1024), dim3(256), 0, stream>>>(w, wbp);
        deform_gemm<true><<<dim3(256), dim3(512), 0, stream>>>(x, off, w, wbp, out);
    } else {
        deform_gemm<false><<<dim3(256), dim3(512), 0, stream>>>(x, off, w, nullptr, out);
    }
}

// Round 2
// 156.361 us; speedup vs baseline: 1.1024x; 1.1024x over previous
//
#include <hip/hip_runtime.h>
#include <hip/hip_bf16.h>
#include <cstdint>

typedef __bf16 bf16x8 __attribute__((ext_vector_type(8)));
typedef float  f32x4  __attribute__((ext_vector_type(4)));

constexpr int KT    = 9;
constexpr int RTOT  = 2304;          // 256 channels * 9 taps, r = c*9 + k
constexpr int RC    = 32;            // K-chunk per step
constexpr int NSTEP = RTOT / RC;     // 72

// ---- one-time fp32 -> bf16 weight conversion into workspace ----
__global__ void weight_to_bf16(const float* __restrict__ w, __bf16* __restrict__ wb) {
    int i = (blockIdx.x * 256 + threadIdx.x) * 4;
    float4 v = *reinterpret_cast<const float4*>(w + i);
    union { ushort4 u; __bf16 h[4]; } o;
    o.h[0] = (__bf16)v.x; o.h[1] = (__bf16)v.y; o.h[2] = (__bf16)v.z; o.h[3] = (__bf16)v.w;
    *reinterpret_cast<ushort4*>(reinterpret_cast<unsigned short*>(wb) + i) = o.u;
}

// Fused deformable-conv implicit GEMM, double-buffered.
// Block = 32 output positions (wo) x 256 output channels; grid = 4*64*2 = 512.
// 256 threads = 4 waves; wave wv computes the 32(M) x 64(N) slab at n0 = wv*64.
template<bool WS>
__global__ __launch_bounds__(256, 2)
void deform_gemm(const float* __restrict__ x, const float* __restrict__ off,
                 const float* __restrict__ wf, const __bf16* __restrict__ wb,
                 float* __restrict__ out) {
    __shared__ float4 s_w[32 * KT];        // bilinear weights, [k][p] layout
    __shared__ int4   s_a[32 * KT];        // clipped corner offsets, [k][p]
    __shared__ unsigned short sA[2][32 * 32];    // A: [p][r] bf16, XOR-swizzled 16B units
    __shared__ unsigned short sB[2][256 * 32];   // B: [co][r] bf16, XOR-swizzled 16B units

    const int tid  = threadIdx.x;
    const int lane = tid & 63;
    const int wv   = tid >> 6;
    const int fr   = lane & 15;
    const int fq   = lane >> 4;

    // XCD-bijective swizzle: 64 consecutive logical blocks per XCD (512 % 8 == 0)
    const int bs  = ((blockIdx.x & 7) << 6) | (blockIdx.x >> 3);
    const int b   = bs >> 7;
    const int ho  = (bs >> 1) & 63;
    const int wo0 = (bs & 1) << 5;

    // ---- per-(k, p) bilinear metadata, conflict-free [k][p] layout ----
    for (int i = tid; i < 32 * KT; i += 256) {
        const int k = i >> 5, p = i & 31, wo = wo0 + p;
        const int kh = k / 3, kw = k - kh * 3;
        const float dy = off[(((b * 18) + 2 * k    ) * 64 + ho) * 64 + wo];
        const float dx = off[(((b * 18) + 2 * k + 1) * 64 + ho) * 64 + wo];
        const float sy = (float)(ho - 1 + kh) + dy;
        const float sx = (float)(wo - 1 + kw) + dx;
        const float y0f = floorf(sy), x0f = floorf(sx);
        const float fy = sy - y0f, fx = sx - x0f;
        const int y0 = (int)y0f, x0 = (int)x0f;
        const int y1 = y0 + 1, x1 = x0 + 1;
        const bool vy0 = (unsigned)y0 < 64u, vy1 = (unsigned)y1 < 64u;
        const bool vx0 = (unsigned)x0 < 64u, vx1 = (unsigned)x1 < 64u;
        const int y0c = min(max(y0, 0), 63), y1c = min(max(y1, 0), 63);
        const int x0c = min(max(x0, 0), 63), x1c = min(max(x1, 0), 63);
        float4 wt;
        wt.x = (1.f - fy) * (1.f - fx) * ((vy0 & vx0) ? 1.f : 0.f);
        wt.y = (1.f - fy) * fx         * ((vy0 & vx1) ? 1.f : 0.f);
        wt.z = fy * (1.f - fx)         * ((vy1 & vx0) ? 1.f : 0.f);
        wt.w = fy * fx                 * ((vy1 & vx1) ? 1.f : 0.f);
        s_w[i] = wt;
        s_a[i] = make_int4((y0c << 6) + x0c, (y0c << 6) + x1c,
                           (y1c << 6) + x0c, (y1c << 6) + x1c);
    }

    f32x4 acc[2][4];
    #pragma unroll
    for (int mf = 0; mf < 2; ++mf)
        #pragma unroll
        for (int nf = 0; nf < 4; ++nf)
            acc[mf][nf] = (f32x4){0.f, 0.f, 0.f, 0.f};

    const float* xb = x + (size_t)b * (256 * 4096);
    const int p  = tid & 31;            // A-gen position
    const int rq = tid >> 5;            // A-gen r-quarter (0..7), rows rq*4+j
    // A write slot: row p, logical unit rq>>1, half rq&1; phys = logical ^ ((p>>1)&3)
    const int aw_off = (p << 5) + ((((rq >> 1) ^ ((p >> 1) & 3)) << 3)) + ((rq & 1) << 2);

    // B staging: 4 insts, each lane-quad covers one full 64B weight line
    int brow[4], bcol[4];
    #pragma unroll
    for (int q = 0; q < 4; ++q) {
        brow[q] = (wv << 6) + (q << 4) + (lane >> 2);
        bcol[q] = ((lane & 3) ^ ((brow[q] >> 1) & 3)) << 3;  // logical col (elements)
    }
    const int bphys = (lane & 3) << 3;  // LDS unit within row (u16 elements)

    __syncthreads();  // meta ready

    // ---- prologue: stage step 0 into buffer 0 ----
    {
        union { ushort4 u; __bf16 h[4]; } pk;
        #pragma unroll
        for (int j = 0; j < 4; ++j) {
            const int r = rq * 4 + j;
            const int c = r / 9, k = r - c * 9;
            const float4 wt = s_w[(k << 5) + p];
            const int4 ad = s_a[(k << 5) + p];
            const float* xp = xb + (c << 12);
            pk.h[j] = (__bf16)(wt.x * xp[ad.x] + wt.y * xp[ad.y]
                             + wt.z * xp[ad.z] + wt.w * xp[ad.w]);
        }
        *reinterpret_cast<ushort4*>(&sA[0][aw_off]) = pk.u;
        #pragma unroll
        for (int q = 0; q < 4; ++q) {
            uint4 v;
            if (WS) {
                v = *reinterpret_cast<const uint4*>(wb + (size_t)brow[q] * RTOT + bcol[q]);
            } else {
                const float4* s = reinterpret_cast<const float4*>(wf + (size_t)brow[q] * RTOT + bcol[q]);
                float4 f0 = s[0], f1 = s[1];
                union { uint4 u; __bf16 h[8]; } ub;
                ub.h[0]=(__bf16)f0.x; ub.h[1]=(__bf16)f0.y; ub.h[2]=(__bf16)f0.z; ub.h[3]=(__bf16)f0.w;
                ub.h[4]=(__bf16)f1.x; ub.h[5]=(__bf16)f1.y; ub.h[6]=(__bf16)f1.z; ub.h[7]=(__bf16)f1.w;
                v = ub.u;
            }
            *reinterpret_cast<uint4*>(&sB[0][(brow[q] << 5) + bphys]) = v;
        }
    }
    __syncthreads();

    // ---- main loop: one barrier per step, prefetch t+1 under MFMA(t) ----
    #pragma unroll 2
    for (int t = 0; t < NSTEP; ++t) {
        const int cur = t & 1;
        const unsigned short* sAc = sA[cur];
        const unsigned short* sBc = sB[cur];

        // 1) fragment reads from current buffer (XOR-swizzled, 2-way max)
        bf16x8 af[2], bfr[4];
        #pragma unroll
        for (int mf = 0; mf < 2; ++mf) {
            const int row = mf * 16 + fr;
            af[mf] = *reinterpret_cast<const bf16x8*>(&sAc[(row << 5) + ((fq ^ ((row >> 1) & 3)) << 3)]);
        }
        #pragma unroll
        for (int nf = 0; nf < 4; ++nf) {
            const int row = (wv << 6) + nf * 16 + fr;
            bfr[nf] = *reinterpret_cast<const bf16x8*>(&sBc[(row << 5) + ((fq ^ ((row >> 1) & 3)) << 3)]);
        }

        // 2) issue next-step loads (A gathers + B lines) before MFMA
        const bool pre = (t + 1 < NSTEP);
        float4 wts[4];
        float g[4][4];
        uint4 breg[4];
        float4 bq0[4], bq1[4];
        if (pre) {
            const int r0 = (t + 1) * RC;
            #pragma unroll
            for (int j = 0; j < 4; ++j) {
                const int r = r0 + rq * 4 + j;
                const int c = r / 9, k = r - c * 9;
                wts[j] = s_w[(k << 5) + p];
                const int4 ad = s_a[(k << 5) + p];
                const float* xp = xb + (c << 12);
                g[j][0] = xp[ad.x]; g[j][1] = xp[ad.y];
                g[j][2] = xp[ad.z]; g[j][3] = xp[ad.w];
            }
            if (WS) {
                #pragma unroll
                for (int q = 0; q < 4; ++q)
                    breg[q] = *reinterpret_cast<const uint4*>(wb + (size_t)brow[q] * RTOT + r0 + bcol[q]);
            } else {
                #pragma unroll
                for (int q = 0; q < 4; ++q) {
                    const float4* s = reinterpret_cast<const float4*>(wf + (size_t)brow[q] * RTOT + r0 + bcol[q]);
                    bq0[q] = s[0]; bq1[q] = s[1];
                }
            }
        }

        // 3) MFMAs on current buffer
        #pragma unroll
        for (int mf = 0; mf < 2; ++mf)
            #pragma unroll
            for (int nf = 0; nf < 4; ++nf)
                acc[mf][nf] = __builtin_amdgcn_mfma_f32_16x16x32_bf16(af[mf], bfr[nf], acc[mf][nf], 0, 0, 0);

        // 4) finish A values, write next buffer
        if (pre) {
            unsigned short* sAn = sA[cur ^ 1];
            unsigned short* sBn = sB[cur ^ 1];
            union { ushort4 u; __bf16 h[4]; } pk;
            #pragma unroll
            for (int j = 0; j < 4; ++j)
                pk.h[j] = (__bf16)(wts[j].x * g[j][0] + wts[j].y * g[j][1]
                                 + wts[j].z * g[j][2] + wts[j].w * g[j][3]);
            *reinterpret_cast<ushort4*>(&sAn[aw_off]) = pk.u;
            #pragma unroll
            for (int q = 0; q < 4; ++q) {
                uint4 v;
                if (WS) {
                    v = breg[q];
                } else {
                    union { uint4 u; __bf16 h[8]; } ub;
                    ub.h[0]=(__bf16)bq0[q].x; ub.h[1]=(__bf16)bq0[q].y; ub.h[2]=(__bf16)bq0[q].z; ub.h[3]=(__bf16)bq0[q].w;
                    ub.h[4]=(__bf16)bq1[q].x; ub.h[5]=(__bf16)bq1[q].y; ub.h[6]=(__bf16)bq1[q].z; ub.h[7]=(__bf16)bq1[q].w;
                    v = ub.u;
                }
                *reinterpret_cast<uint4*>(&sBn[(brow[q] << 5) + bphys]) = v;
            }
        }
        __syncthreads();
    }

    // ---- epilogue: D[m][n] -> out[b][n][ho][wo0+m], float4 over consecutive wo ----
    float* ob = out + (size_t)b * (256 * 4096) + (ho << 6) + wo0;
    #pragma unroll
    for (int nf = 0; nf < 4; ++nf) {
        const int n = (wv << 6) + nf * 16 + fr;
        #pragma unroll
        for (int mf = 0; mf < 2; ++mf) {
            const int m = mf * 16 + (fq << 2);
            *reinterpret_cast<f32x4*>(&ob[(size_t)n * 4096 + m]) = acc[mf][nf];
        }
    }
}

extern "C" void kernel_launch(void* const* d_in, const int* in_sizes, int n_in,
                              void* d_out, int out_size, void* d_ws, size_t ws_size,
                              hipStream_t stream) {
    const float* x   = (const float*)d_in[0];
    const float* off = (const float*)d_in[1];
    const float* w   = (const float*)d_in[2];
    float* out = (float*)d_out;

    const size_t wb_bytes = (size_t)256 * RTOT * sizeof(__bf16); // 1.18 MB
    if (ws_size >= wb_bytes) {
        __bf16* wbp = (__bf16*)d_ws;
        weight_to_bf16<<<dim3(576), dim3(256), 0, stream>>>(w, wbp);
        deform_gemm<true><<<dim3(512), dim3(256), 0, stream>>>(x, off, w, wbp, out);
    } else {
        deform_gemm<false><<<dim3(512), dim3(256), 0, stream>>>(x, off, w, nullptr, out);
    }
}

// Round 3
// 85.619 us; speedup vs baseline: 2.0133x; 1.8262x over previous
//
#include <hip/hip_runtime.h>
#include <hip/hip_bf16.h>
#include <cstdint>

typedef __bf16 bf16x8 __attribute__((ext_vector_type(8)));
typedef float  f32x4  __attribute__((ext_vector_type(4)));

constexpr int RTOT  = 2304;          // 9 taps * 256 channels, r = k*256 + c
constexpr int RC    = 32;
constexpr int NSTEP = RTOT / RC;     // 72

__device__ __forceinline__ float bf2f(unsigned short u) {
    union { unsigned int i; float f; } v; v.i = ((unsigned int)u) << 16; return v.f;
}

__device__ __forceinline__ void gload_lds16(const void* g, void* l) {
    __builtin_amdgcn_global_load_lds(
        (const __attribute__((address_space(1))) unsigned int*)g,
        (__attribute__((address_space(3))) unsigned int*)l, 16, 0, 0);
}

// ---- prep 1: x [4,256,64,64] f32 (NCHW) -> xh [4,64,64,256] bf16 (NHWC) ----
__global__ __launch_bounds__(256)
void nchw_to_nhwc_bf16(const float* __restrict__ x, __bf16* __restrict__ xh) {
    __shared__ unsigned short tile[256][70];   // pad 70: stride 35 words, conflict-free col reads
    const int tid = threadIdx.x;
    const int b = blockIdx.x >> 6;
    const int y = blockIdx.x & 63;
    const float* xp = x + (size_t)b * (256 * 4096) + y * 64;
    #pragma unroll 4
    for (int it = 0; it < 64; ++it) {
        const int ci = it * 4 + (tid >> 6);
        const int xi = tid & 63;
        __bf16 h = (__bf16)xp[(size_t)ci * 4096 + xi];
        tile[ci][xi] = *reinterpret_cast<unsigned short*>(&h);
    }
    __syncthreads();
    unsigned short* op = reinterpret_cast<unsigned short*>(xh) + ((size_t)b * 64 + y) * 64 * 256;
    #pragma unroll 4
    for (int it = 0; it < 64; ++it)
        op[(size_t)it * 256 + tid] = tile[tid][it];
}

// ---- prep 2: w [co][c][k] f32 -> wb [co][k*256+c] bf16 ----
__global__ __launch_bounds__(256)
void weight_prep(const float* __restrict__ w, __bf16* __restrict__ wb) {
    const int o = (blockIdx.x * 256 + threadIdx.x) * 4;  // co*2304 + k*256 + c
    const int co = o / 2304;
    const int rem = o - co * 2304;
    const int k = rem >> 8;
    const int c = rem & 255;
    union { ushort4 u; __bf16 h[4]; } pk;
    #pragma unroll
    for (int j = 0; j < 4; ++j)
        pk.h[j] = (__bf16)w[co * 2304 + (c + j) * 9 + k];
    *reinterpret_cast<ushort4*>(reinterpret_cast<unsigned short*>(wb) + o) = pk.u;
}

// ---- main: fused deformable implicit GEMM on NHWC bf16 ----
// Block = 32 wo x 256 co, 256 threads / 4 waves, wave = 32(M) x 64(N).
// Step t: k = t>>3 fixed, channels c0 = (t&7)*32 .. +31.
__global__ __launch_bounds__(256, 2)
void deform_gemm_nhwc(const float* __restrict__ off, const __bf16* __restrict__ xh,
                      const __bf16* __restrict__ wb, float* __restrict__ out) {
    __shared__ float4 s_w[32 * 9];
    __shared__ int4   s_a[32 * 9];               // spatial corner indices y*64+x
    __shared__ unsigned short sA[2][32 * 32];    // [p][r], XOR-swizzled 16B units
    __shared__ unsigned short sB[2][256 * 32];   // [co][r], XOR-swizzled 16B units

    const int tid  = threadIdx.x;
    const int lane = tid & 63;
    const int wv   = tid >> 6;
    const int fr   = lane & 15;
    const int fq   = lane >> 4;

    const int bs  = ((blockIdx.x & 7) << 6) | (blockIdx.x >> 3);  // XCD swizzle, bijective (512%8==0)
    const int b   = bs >> 7;
    const int ho  = (bs >> 1) & 63;
    const int wo0 = (bs & 1) << 5;

    for (int i = tid; i < 32 * 9; i += 256) {
        const int k = i >> 5, p = i & 31, wo = wo0 + p;
        const int kh = k / 3, kw = k - kh * 3;
        const float dy = off[(((b * 18) + 2 * k    ) * 64 + ho) * 64 + wo];
        const float dx = off[(((b * 18) + 2 * k + 1) * 64 + ho) * 64 + wo];
        const float sy = (float)(ho - 1 + kh) + dy;
        const float sx = (float)(wo - 1 + kw) + dx;
        const float y0f = floorf(sy), x0f = floorf(sx);
        const float fy = sy - y0f, fx = sx - x0f;
        const int y0 = (int)y0f, x0 = (int)x0f;
        const int y1 = y0 + 1, x1 = x0 + 1;
        const bool vy0 = (unsigned)y0 < 64u, vy1 = (unsigned)y1 < 64u;
        const bool vx0 = (unsigned)x0 < 64u, vx1 = (unsigned)x1 < 64u;
        const int y0c = min(max(y0, 0), 63), y1c = min(max(y1, 0), 63);
        const int x0c = min(max(x0, 0), 63), x1c = min(max(x1, 0), 63);
        float4 wt;
        wt.x = (1.f - fy) * (1.f - fx) * ((vy0 & vx0) ? 1.f : 0.f);
        wt.y = (1.f - fy) * fx         * ((vy0 & vx1) ? 1.f : 0.f);
        wt.z = fy * (1.f - fx)         * ((vy1 & vx0) ? 1.f : 0.f);
        wt.w = fy * fx                 * ((vy1 & vx1) ? 1.f : 0.f);
        s_w[i] = wt;
        s_a[i] = make_int4((y0c << 6) + x0c, (y0c << 6) + x1c,
                           (y1c << 6) + x0c, (y1c << 6) + x1c);
    }

    f32x4 acc[2][4];
    #pragma unroll
    for (int mf = 0; mf < 2; ++mf)
        #pragma unroll
        for (int nf = 0; nf < 4; ++nf)
            acc[mf][nf] = (f32x4){0.f, 0.f, 0.f, 0.f};

    const __bf16* xb = xh + ((size_t)b << 20);   // b * 64*64*256
    const int p  = tid >> 3;                     // A-gen position (0..31)
    const int cl = tid & 7;                      // channel quad (c = c0 + cl*4)
    const int aw_off = (p << 5) + ((((cl >> 1) ^ ((p >> 1) & 3)) << 3)) + ((cl & 1) << 2);

    // B staging via global_load_lds: wave stages its own 64-row slab, 4 x 1KB chunks.
    // Linear LDS dest (lane*16); source pre-swizzled so swizzled reads see logical data.
    const __bf16* gpB[4];
    int bofs[4];
    #pragma unroll
    for (int q = 0; q < 4; ++q) {
        const int row = (wv << 6) + (q << 4) + (lane >> 2);
        const int u = (lane & 3) ^ ((row >> 1) & 3);
        gpB[q] = wb + (size_t)row * RTOT + (u << 3);
        bofs[q] = ((wv << 6) + (q << 4)) << 5;
    }

    __syncthreads();  // meta ready

    // ---- prologue: stage step 0 ----
    {
        const float4 wt = s_w[p];               // k=0
        const int4 sa = s_a[p];
        const int cc = cl << 2;                 // c0 = 0
        const ushort4 g0 = *reinterpret_cast<const ushort4*>(xb + ((size_t)sa.x << 8) + cc);
        const ushort4 g1 = *reinterpret_cast<const ushort4*>(xb + ((size_t)sa.y << 8) + cc);
        const ushort4 g2 = *reinterpret_cast<const ushort4*>(xb + ((size_t)sa.z << 8) + cc);
        const ushort4 g3 = *reinterpret_cast<const ushort4*>(xb + ((size_t)sa.w << 8) + cc);
        union { ushort4 u; __bf16 h[4]; } pk;
        const unsigned short* a0 = reinterpret_cast<const unsigned short*>(&g0);
        const unsigned short* a1 = reinterpret_cast<const unsigned short*>(&g1);
        const unsigned short* a2 = reinterpret_cast<const unsigned short*>(&g2);
        const unsigned short* a3 = reinterpret_cast<const unsigned short*>(&g3);
        #pragma unroll
        for (int j = 0; j < 4; ++j)
            pk.h[j] = (__bf16)(wt.x * bf2f(a0[j]) + wt.y * bf2f(a1[j])
                             + wt.z * bf2f(a2[j]) + wt.w * bf2f(a3[j]));
        *reinterpret_cast<ushort4*>(&sA[0][aw_off]) = pk.u;
        #pragma unroll
        for (int q = 0; q < 4; ++q)
            gload_lds16(gpB[q], &sB[0][bofs[q]]);
    }
    __syncthreads();

    // ---- main loop ----
    #pragma unroll 2
    for (int t = 0; t < NSTEP; ++t) {
        const int cur = t & 1;
        const unsigned short* sAc = sA[cur];
        const unsigned short* sBc = sB[cur];

        // 1) fragment reads (2-way max conflicts)
        bf16x8 af[2], bfr[4];
        #pragma unroll
        for (int mf = 0; mf < 2; ++mf) {
            const int row = mf * 16 + fr;
            af[mf] = *reinterpret_cast<const bf16x8*>(&sAc[(row << 5) + ((fq ^ ((row >> 1) & 3)) << 3)]);
        }
        #pragma unroll
        for (int nf = 0; nf < 4; ++nf) {
            const int row = (wv << 6) + nf * 16 + fr;
            bfr[nf] = *reinterpret_cast<const bf16x8*>(&sBc[(row << 5) + ((fq ^ ((row >> 1) & 3)) << 3)]);
        }

        // 2) issue t+1 loads: A corner gathers (coalesced ushort4) then B gload_lds
        const bool pre = (t + 1 < NSTEP);
        float4 wt; int4 sa;
        ushort4 g0, g1, g2, g3;
        if (pre) {
            const int tn = t + 1;
            const int kn = tn >> 3;
            const int cc = ((tn & 7) << 5) + (cl << 2);
            wt = s_w[(kn << 5) + p];
            sa = s_a[(kn << 5) + p];
            g0 = *reinterpret_cast<const ushort4*>(xb + ((size_t)sa.x << 8) + cc);
            g1 = *reinterpret_cast<const ushort4*>(xb + ((size_t)sa.y << 8) + cc);
            g2 = *reinterpret_cast<const ushort4*>(xb + ((size_t)sa.z << 8) + cc);
            g3 = *reinterpret_cast<const ushort4*>(xb + ((size_t)sa.w << 8) + cc);
            const int r0n = tn << 5;
            #pragma unroll
            for (int q = 0; q < 4; ++q)
                gload_lds16(gpB[q] + r0n, &sB[cur ^ 1][bofs[q]]);
        }

        // 3) MFMAs on current buffers
        #pragma unroll
        for (int mf = 0; mf < 2; ++mf)
            #pragma unroll
            for (int nf = 0; nf < 4; ++nf)
                acc[mf][nf] = __builtin_amdgcn_mfma_f32_16x16x32_bf16(af[mf], bfr[nf], acc[mf][nf], 0, 0, 0);

        // 4) finish A(t+1): bilinear combine, write next buffer
        if (pre) {
            union { ushort4 u; __bf16 h[4]; } pk;
            const unsigned short* a0 = reinterpret_cast<const unsigned short*>(&g0);
            const unsigned short* a1 = reinterpret_cast<const unsigned short*>(&g1);
            const unsigned short* a2 = reinterpret_cast<const unsigned short*>(&g2);
            const unsigned short* a3 = reinterpret_cast<const unsigned short*>(&g3);
            #pragma unroll
            for (int j = 0; j < 4; ++j)
                pk.h[j] = (__bf16)(wt.x * bf2f(a0[j]) + wt.y * bf2f(a1[j])
                                 + wt.z * bf2f(a2[j]) + wt.w * bf2f(a3[j]));
            *reinterpret_cast<ushort4*>(&sA[cur ^ 1][aw_off]) = pk.u;
        }
        __syncthreads();   // also drains gload_lds (vmcnt) for next step
    }

    // ---- epilogue ----
    float* ob = out + (size_t)b * (256 * 4096) + (ho << 6) + wo0;
    #pragma unroll
    for (int nf = 0; nf < 4; ++nf) {
        const int n = (wv << 6) + nf * 16 + fr;
        #pragma unroll
        for (int mf = 0; mf < 2; ++mf) {
            const int m = mf * 16 + (fq << 2);
            *reinterpret_cast<f32x4*>(&ob[(size_t)n * 4096 + m]) = acc[mf][nf];
        }
    }
}

// ---- fallback (ws too small): round-2 kernel, convert-on-the-fly weights ----
__global__ __launch_bounds__(256, 2)
void deform_gemm_fb(const float* __restrict__ x, const float* __restrict__ off,
                    const float* __restrict__ wf, float* __restrict__ out) {
    __shared__ float4 s_w[32 * 9];
    __shared__ int4   s_a[32 * 9];
    __shared__ unsigned short sA[2][32 * 32];
    __shared__ unsigned short sB[2][256 * 32];

    const int tid  = threadIdx.x;
    const int lane = tid & 63;
    const int wv   = tid >> 6;
    const int fr   = lane & 15;
    const int fq   = lane >> 4;
    const int bs  = ((blockIdx.x & 7) << 6) | (blockIdx.x >> 3);
    const int b   = bs >> 7;
    const int ho  = (bs >> 1) & 63;
    const int wo0 = (bs & 1) << 5;

    for (int i = tid; i < 32 * 9; i += 256) {
        const int k = i >> 5, p = i & 31, wo = wo0 + p;
        const int kh = k / 3, kw = k - kh * 3;
        const float dy = off[(((b * 18) + 2 * k    ) * 64 + ho) * 64 + wo];
        const float dx = off[(((b * 18) + 2 * k + 1) * 64 + ho) * 64 + wo];
        const float sy = (float)(ho - 1 + kh) + dy;
        const float sx = (float)(wo - 1 + kw) + dx;
        const float y0f = floorf(sy), x0f = floorf(sx);
        const float fy = sy - y0f, fx = sx - x0f;
        const int y0 = (int)y0f, x0 = (int)x0f;
        const int y1 = y0 + 1, x1 = x0 + 1;
        const bool vy0 = (unsigned)y0 < 64u, vy1 = (unsigned)y1 < 64u;
        const bool vx0 = (unsigned)x0 < 64u, vx1 = (unsigned)x1 < 64u;
        const int y0c = min(max(y0, 0), 63), y1c = min(max(y1, 0), 63);
        const int x0c = min(max(x0, 0), 63), x1c = min(max(x1, 0), 63);
        float4 wt;
        wt.x = (1.f - fy) * (1.f - fx) * ((vy0 & vx0) ? 1.f : 0.f);
        wt.y = (1.f - fy) * fx         * ((vy0 & vx1) ? 1.f : 0.f);
        wt.z = fy * (1.f - fx)         * ((vy1 & vx0) ? 1.f : 0.f);
        wt.w = fy * fx                 * ((vy1 & vx1) ? 1.f : 0.f);
        s_w[i] = wt;
        s_a[i] = make_int4((y0c << 6) + x0c, (y0c << 6) + x1c,
                           (y1c << 6) + x0c, (y1c << 6) + x1c);
    }

    f32x4 acc[2][4];
    #pragma unroll
    for (int mf = 0; mf < 2; ++mf)
        #pragma unroll
        for (int nf = 0; nf < 4; ++nf)
            acc[mf][nf] = (f32x4){0.f, 0.f, 0.f, 0.f};

    const float* xb = x + (size_t)b * (256 * 4096);
    const int p  = tid & 31;
    const int rq = tid >> 5;
    const int aw_off = (p << 5) + ((((rq >> 1) ^ ((p >> 1) & 3)) << 3)) + ((rq & 1) << 2);

    int brow[4], bcol[4];
    #pragma unroll
    for (int q = 0; q < 4; ++q) {
        brow[q] = (wv << 6) + (q << 4) + (lane >> 2);
        bcol[q] = ((lane & 3) ^ ((brow[q] >> 1) & 3)) << 3;
    }
    const int bphys = (lane & 3) << 3;

    __syncthreads();

    for (int t = 0; t < NSTEP; ++t) {
        const int cur = t & 1;
        const int r0 = t * RC;
        // stage current (single-buffered simplicity for fallback)
        union { ushort4 u; __bf16 h[4]; } pk;
        #pragma unroll
        for (int j = 0; j < 4; ++j) {
            const int r = r0 + rq * 4 + j;
            const int c = r / 9, k = r - c * 9;
            const float4 wt = s_w[(k << 5) + p];
            const int4 ad = s_a[(k << 5) + p];
            const float* xp = xb + (c << 12);
            pk.h[j] = (__bf16)(wt.x * xp[ad.x] + wt.y * xp[ad.y]
                             + wt.z * xp[ad.z] + wt.w * xp[ad.w]);
        }
        *reinterpret_cast<ushort4*>(&sA[cur][aw_off]) = pk.u;
        #pragma unroll
        for (int q = 0; q < 4; ++q) {
            const float4* s = reinterpret_cast<const float4*>(wf + (size_t)brow[q] * RTOT + r0 + bcol[q]);
            float4 f0 = s[0], f1 = s[1];
            union { uint4 u; __bf16 h[8]; } ub;
            ub.h[0]=(__bf16)f0.x; ub.h[1]=(__bf16)f0.y; ub.h[2]=(__bf16)f0.z; ub.h[3]=(__bf16)f0.w;
            ub.h[4]=(__bf16)f1.x; ub.h[5]=(__bf16)f1.y; ub.h[6]=(__bf16)f1.z; ub.h[7]=(__bf16)f1.w;
            *reinterpret_cast<uint4*>(&sB[cur][(brow[q] << 5) + bphys]) = ub.u;
        }
        __syncthreads();
        bf16x8 af[2], bfr[4];
        #pragma unroll
        for (int mf = 0; mf < 2; ++mf) {
            const int row = mf * 16 + fr;
            af[mf] = *reinterpret_cast<const bf16x8*>(&sA[cur][(row << 5) + ((fq ^ ((row >> 1) & 3)) << 3)]);
        }
        #pragma unroll
        for (int nf = 0; nf < 4; ++nf) {
            const int row = (wv << 6) + nf * 16 + fr;
            bfr[nf] = *reinterpret_cast<const bf16x8*>(&sB[cur][(row << 5) + ((fq ^ ((row >> 1) & 3)) << 3)]);
        }
        #pragma unroll
        for (int mf = 0; mf < 2; ++mf)
            #pragma unroll
            for (int nf = 0; nf < 4; ++nf)
                acc[mf][nf] = __builtin_amdgcn_mfma_f32_16x16x32_bf16(af[mf], bfr[nf], acc[mf][nf], 0, 0, 0);
        __syncthreads();
    }

    float* ob = out + (size_t)b * (256 * 4096) + (ho << 6) + wo0;
    #pragma unroll
    for (int nf = 0; nf < 4; ++nf) {
        const int n = (wv << 6) + nf * 16 + fr;
        #pragma unroll
        for (int mf = 0; mf < 2; ++mf) {
            const int m = mf * 16 + (fq << 2);
            *reinterpret_cast<f32x4*>(&ob[(size_t)n * 4096 + m]) = acc[mf][nf];
        }
    }
}

extern "C" void kernel_launch(void* const* d_in, const int* in_sizes, int n_in,
                              void* d_out, int out_size, void* d_ws, size_t ws_size,
                              hipStream_t stream) {
    const float* x   = (const float*)d_in[0];
    const float* off = (const float*)d_in[1];
    const float* w   = (const float*)d_in[2];
    float* out = (float*)d_out;

    const size_t xh_bytes = (size_t)4 * 64 * 64 * 256 * sizeof(__bf16);   // 8.4 MB
    const size_t wb_bytes = (size_t)256 * RTOT * sizeof(__bf16);          // 1.18 MB
    if (ws_size >= xh_bytes + wb_bytes) {
        __bf16* xh = (__bf16*)d_ws;
        __bf16* wb = (__bf16*)((char*)d_ws + xh_bytes);
        nchw_to_nhwc_bf16<<<dim3(256), dim3(256), 0, stream>>>(x, xh);
        weight_prep<<<dim3(576), dim3(256), 0, stream>>>(w, wb);
        deform_gemm_nhwc<<<dim3(512), dim3(256), 0, stream>>>(off, xh, wb, out);
    } else {
        deform_gemm_fb<<<dim3(512), dim3(256), 0, stream>>>(x, off, w, out);
    }
}

// Round 4
// 79.002 us; speedup vs baseline: 2.1819x; 1.0838x over previous
//
#include <hip/hip_runtime.h>
#include <hip/hip_bf16.h>
#include <cstdint>

typedef __bf16 bf16x8 __attribute__((ext_vector_type(8)));
typedef float  f32x4  __attribute__((ext_vector_type(4)));
typedef unsigned short ushort8 __attribute__((ext_vector_type(8)));

constexpr int RTOT  = 2304;          // 9 taps * 256 channels, r = k*256 + c
constexpr int RC    = 32;
constexpr int NSTEP = RTOT / RC;     // 72

#define WAITV4  asm volatile("s_waitcnt vmcnt(4)" ::: "memory")
#define WAITV0  asm volatile("s_waitcnt vmcnt(0)" ::: "memory")
#define WAITLGKM0 asm volatile("s_waitcnt lgkmcnt(0)" ::: "memory")
#define SCHEDB  __builtin_amdgcn_sched_barrier(0)

__device__ __forceinline__ float bf2f(unsigned short u) {
    union { unsigned int i; float f; } v; v.i = ((unsigned int)u) << 16; return v.f;
}

__device__ __forceinline__ void gload_lds16(const void* g, void* l) {
    __builtin_amdgcn_global_load_lds(
        (const __attribute__((address_space(1))) unsigned int*)g,
        (__attribute__((address_space(3))) unsigned int*)l, 16, 0, 0);
}

// ---- prep 1: x [4,256,64,64] f32 (NCHW) -> xh [4,64,64,256] bf16 (NHWC) ----
__global__ __launch_bounds__(256)
void nchw_to_nhwc_bf16(const float* __restrict__ x, __bf16* __restrict__ xh) {
    __shared__ unsigned short tile[256][70];
    const int tid = threadIdx.x;
    const int b = blockIdx.x >> 6;
    const int y = blockIdx.x & 63;
    const float* xp = x + (size_t)b * (256 * 4096) + y * 64;
    #pragma unroll 4
    for (int it = 0; it < 64; ++it) {
        const int ci = it * 4 + (tid >> 6);
        const int xi = tid & 63;
        __bf16 h = (__bf16)xp[(size_t)ci * 4096 + xi];
        tile[ci][xi] = *reinterpret_cast<unsigned short*>(&h);
    }
    __syncthreads();
    unsigned short* op = reinterpret_cast<unsigned short*>(xh) + ((size_t)b * 64 + y) * 64 * 256;
    #pragma unroll 4
    for (int it = 0; it < 64; ++it)
        op[(size_t)it * 256 + tid] = tile[tid][it];
}

// ---- prep 2: w [co][c][k] f32 -> wb [co][k*256+c] bf16 ----
__global__ __launch_bounds__(256)
void weight_prep(const float* __restrict__ w, __bf16* __restrict__ wb) {
    const int o = (blockIdx.x * 256 + threadIdx.x) * 4;
    const int co = o / 2304;
    const int rem = o - co * 2304;
    const int k = rem >> 8;
    const int c = rem & 255;
    union { ushort4 u; __bf16 h[4]; } pk;
    #pragma unroll
    for (int j = 0; j < 4; ++j)
        pk.h[j] = (__bf16)w[co * 2304 + (c + j) * 9 + k];
    *reinterpret_cast<ushort4*>(reinterpret_cast<unsigned short*>(wb) + o) = pk.u;
}

// ---- main: fused deformable implicit GEMM, counted-vmcnt raw-barrier pipeline ----
// Block = 32 wo x 256 co, 256 threads / 4 waves; wave = 32(M) x 64(N) slab.
// Step t: tap k = t>>3, channels c0 = (t&7)*32.
// VMEM issue order per step: B gload_lds(t+1) x4, then A gathers(t+2) x4.
// Pre-barrier wait = vmcnt(4): B landed, A(t+2) stays in flight across the barrier.
__global__ __launch_bounds__(256, 2)
void deform_gemm_nhwc(const float* __restrict__ off, const __bf16* __restrict__ xh,
                      const __bf16* __restrict__ wb, float* __restrict__ out) {
    __shared__ float4 s_w[32 * 9];
    __shared__ int4   s_a[32 * 9];
    __shared__ unsigned short sA[2][32 * 32];    // [p][r], XOR-swizzled 16B units
    __shared__ unsigned short sB[2][256 * 32];   // [co][r], XOR-swizzled 16B units

    const int tid  = threadIdx.x;
    const int lane = tid & 63;
    const int wv   = tid >> 6;
    const int fr   = lane & 15;
    const int fq   = lane >> 4;

    const int bs  = ((blockIdx.x & 7) << 6) | (blockIdx.x >> 3);  // bijective XCD swizzle
    const int b   = bs >> 7;
    const int ho  = (bs >> 1) & 63;
    const int wo0 = (bs & 1) << 5;

    for (int i = tid; i < 32 * 9; i += 256) {
        const int k = i >> 5, p = i & 31, wo = wo0 + p;
        const int kh = k / 3, kw = k - kh * 3;
        const float dy = off[(((b * 18) + 2 * k    ) * 64 + ho) * 64 + wo];
        const float dx = off[(((b * 18) + 2 * k + 1) * 64 + ho) * 64 + wo];
        const float sy = (float)(ho - 1 + kh) + dy;
        const float sx = (float)(wo - 1 + kw) + dx;
        const float y0f = floorf(sy), x0f = floorf(sx);
        const float fy = sy - y0f, fx = sx - x0f;
        const int y0 = (int)y0f, x0 = (int)x0f;
        const int y1 = y0 + 1, x1 = x0 + 1;
        const bool vy0 = (unsigned)y0 < 64u, vy1 = (unsigned)y1 < 64u;
        const bool vx0 = (unsigned)x0 < 64u, vx1 = (unsigned)x1 < 64u;
        const int y0c = min(max(y0, 0), 63), y1c = min(max(y1, 0), 63);
        const int x0c = min(max(x0, 0), 63), x1c = min(max(x1, 0), 63);
        float4 wt;
        wt.x = (1.f - fy) * (1.f - fx) * ((vy0 & vx0) ? 1.f : 0.f);
        wt.y = (1.f - fy) * fx         * ((vy0 & vx1) ? 1.f : 0.f);
        wt.z = fy * (1.f - fx)         * ((vy1 & vx0) ? 1.f : 0.f);
        wt.w = fy * fx                 * ((vy1 & vx1) ? 1.f : 0.f);
        s_w[i] = wt;
        s_a[i] = make_int4((y0c << 6) + x0c, (y0c << 6) + x1c,
                           (y1c << 6) + x0c, (y1c << 6) + x1c);
    }

    f32x4 acc[2][4];
    #pragma unroll
    for (int mf = 0; mf < 2; ++mf)
        #pragma unroll
        for (int nf = 0; nf < 4; ++nf)
            acc[mf][nf] = (f32x4){0.f, 0.f, 0.f, 0.f};

    const __bf16* xb = xh + ((size_t)b << 20);
    // A-gen: 128 active lanes (lane<32 of each wave). ai = wv*32 + lane.
    const bool agen = (lane < 32);
    const int ai = (wv << 5) + (lane & 31);
    const int p  = ai >> 2;                 // position 0..31
    const int cl = ai & 3;                  // channel octet: c = c0 + cl*8
    const int aw_off = (p << 5) + ((cl ^ ((p >> 1) & 3)) << 3);  // 16B unit

    // B staging sources (pre-swizzled so linear gload_lds dest + swizzled read match)
    const __bf16* gpB[4];
    int bofs[4];
    #pragma unroll
    for (int q = 0; q < 4; ++q) {
        const int row = (wv << 6) + (q << 4) + (lane >> 2);
        const int u = (lane & 3) ^ ((row >> 1) & 3);
        gpB[q] = wb + (size_t)row * RTOT + (u << 3);
        bofs[q] = ((wv << 6) + (q << 4)) << 5;
    }

    __syncthreads();  // meta ready (plain barrier OK outside pipeline)

    float4  wt_pend;
    ushort8 ga0, ga1, ga2, ga3;

    // ---- prologue: stage step 0, then issue A(1) ----
    {
        #pragma unroll
        for (int q = 0; q < 4; ++q)
            gload_lds16(gpB[q], &sB[0][bofs[q]]);
        if (agen) {
            const float4 wt = s_w[p];           // k=0
            const int4 sa = s_a[p];
            const int cc = cl << 3;             // c0=0
            ga0 = *reinterpret_cast<const ushort8*>(xb + ((size_t)sa.x << 8) + cc);
            ga1 = *reinterpret_cast<const ushort8*>(xb + ((size_t)sa.y << 8) + cc);
            ga2 = *reinterpret_cast<const ushort8*>(xb + ((size_t)sa.z << 8) + cc);
            ga3 = *reinterpret_cast<const ushort8*>(xb + ((size_t)sa.w << 8) + cc);
            WAITV0;
            union { ushort8 u; __bf16 h[8]; } pk;
            #pragma unroll
            for (int j = 0; j < 8; ++j)
                pk.h[j] = (__bf16)(wt.x * bf2f(ga0[j]) + wt.y * bf2f(ga1[j])
                                 + wt.z * bf2f(ga2[j]) + wt.w * bf2f(ga3[j]));
            *reinterpret_cast<ushort8*>(&sA[0][aw_off]) = pk.u;
        }
        WAITV0;   // all waves: sB[0] landed
        // issue A(1)
        if (agen) {
            const int kn = 1 >> 3;              // 0
            const int cc = ((1 & 7) << 5) + (cl << 3);
            wt_pend = s_w[(kn << 5) + p];
            const int4 sa = s_a[(kn << 5) + p];
            ga0 = *reinterpret_cast<const ushort8*>(xb + ((size_t)sa.x << 8) + cc);
            ga1 = *reinterpret_cast<const ushort8*>(xb + ((size_t)sa.y << 8) + cc);
            ga2 = *reinterpret_cast<const ushort8*>(xb + ((size_t)sa.z << 8) + cc);
            ga3 = *reinterpret_cast<const ushort8*>(xb + ((size_t)sa.w << 8) + cc);
        }
        WAITLGKM0;
        __builtin_amdgcn_s_barrier();
        SCHEDB;
    }

    // ---- main loop: t = 0..70 computes step t, preps t+1, issues A(t+2) ----
    #pragma unroll 2
    for (int t = 0; t < NSTEP - 1; ++t) {
        const int cur = t & 1;
        const unsigned short* sAc = sA[cur];
        const unsigned short* sBc = sB[cur];
        unsigned short* sAn = const_cast<unsigned short*>(sA[cur ^ 1]);
        unsigned short* sBn = const_cast<unsigned short*>(sB[cur ^ 1]);

        // 1) fragment reads from current buffers
        bf16x8 af[2], bfr[4];
        #pragma unroll
        for (int mf = 0; mf < 2; ++mf) {
            const int row = mf * 16 + fr;
            af[mf] = *reinterpret_cast<const bf16x8*>(&sAc[(row << 5) + ((fq ^ ((row >> 1) & 3)) << 3)]);
        }
        #pragma unroll
        for (int nf = 0; nf < 4; ++nf) {
            const int row = (wv << 6) + nf * 16 + fr;
            bfr[nf] = *reinterpret_cast<const bf16x8*>(&sBc[(row << 5) + ((fq ^ ((row >> 1) & 3)) << 3)]);
        }

        // 2) issue B(t+1) gload_lds (oldest VMEM of this step)
        {
            const int r0n = (t + 1) << 5;
            #pragma unroll
            for (int q = 0; q < 4; ++q)
                gload_lds16(gpB[q] + r0n, &sBn[bofs[q]]);
        }
        SCHEDB;

        // 3) MFMAs on current buffers
        __builtin_amdgcn_s_setprio(1);
        #pragma unroll
        for (int mf = 0; mf < 2; ++mf)
            #pragma unroll
            for (int nf = 0; nf < 4; ++nf)
                acc[mf][nf] = __builtin_amdgcn_mfma_f32_16x16x32_bf16(af[mf], bfr[nf], acc[mf][nf], 0, 0, 0);
        __builtin_amdgcn_s_setprio(0);

        // 4) combine A(t+1) (compiler inserts counted vmcnt for ga deps), write sA[nxt]
        if (agen) {
            union { ushort8 u; __bf16 h[8]; } pk;
            #pragma unroll
            for (int j = 0; j < 8; ++j)
                pk.h[j] = (__bf16)(wt_pend.x * bf2f(ga0[j]) + wt_pend.y * bf2f(ga1[j])
                                 + wt_pend.z * bf2f(ga2[j]) + wt_pend.w * bf2f(ga3[j]));
            *reinterpret_cast<ushort8*>(&sAn[aw_off]) = pk.u;
        }
        SCHEDB;

        // 5) issue A(t+2) — stays in flight across the barrier
        if (t < NSTEP - 2) {
            if (agen) {
                const int tn = t + 2;
                const int kn = tn >> 3;
                const int cc = ((tn & 7) << 5) + (cl << 3);
                wt_pend = s_w[(kn << 5) + p];
                const int4 sa = s_a[(kn << 5) + p];
                ga0 = *reinterpret_cast<const ushort8*>(xb + ((size_t)sa.x << 8) + cc);
                ga1 = *reinterpret_cast<const ushort8*>(xb + ((size_t)sa.y << 8) + cc);
                ga2 = *reinterpret_cast<const ushort8*>(xb + ((size_t)sa.z << 8) + cc);
                ga3 = *reinterpret_cast<const ushort8*>(xb + ((size_t)sa.w << 8) + cc);
            }
            SCHEDB;
            WAITV4;      // B(t+1) landed; A(t+2) x4 still outstanding
        } else {
            SCHEDB;
            WAITV0;      // tail: drain everything
        }
        WAITLGKM0;       // ds_write visible
        __builtin_amdgcn_s_barrier();
        SCHEDB;
    }

    // ---- final step t = 71 ----
    {
        const int cur = (NSTEP - 1) & 1;
        const unsigned short* sAc = sA[cur];
        const unsigned short* sBc = sB[cur];
        bf16x8 af[2], bfr[4];
        #pragma unroll
        for (int mf = 0; mf < 2; ++mf) {
            const int row = mf * 16 + fr;
            af[mf] = *reinterpret_cast<const bf16x8*>(&sAc[(row << 5) + ((fq ^ ((row >> 1) & 3)) << 3)]);
        }
        #pragma unroll
        for (int nf = 0; nf < 4; ++nf) {
            const int row = (wv << 6) + nf * 16 + fr;
            bfr[nf] = *reinterpret_cast<const bf16x8*>(&sBc[(row << 5) + ((fq ^ ((row >> 1) & 3)) << 3)]);
        }
        #pragma unroll
        for (int mf = 0; mf < 2; ++mf)
            #pragma unroll
            for (int nf = 0; nf < 4; ++nf)
                acc[mf][nf] = __builtin_amdgcn_mfma_f32_16x16x32_bf16(af[mf], bfr[nf], acc[mf][nf], 0, 0, 0);
    }

    // ---- epilogue ----
    float* ob = out + (size_t)b * (256 * 4096) + (ho << 6) + wo0;
    #pragma unroll
    for (int nf = 0; nf < 4; ++nf) {
        const int n = (wv << 6) + nf * 16 + fr;
        #pragma unroll
        for (int mf = 0; mf < 2; ++mf) {
            const int m = mf * 16 + (fq << 2);
            *reinterpret_cast<f32x4*>(&ob[(size_t)n * 4096 + m]) = acc[mf][nf];
        }
    }
}

// ---- fallback (ws too small): round-2 style, convert-on-the-fly weights ----
__global__ __launch_bounds__(256, 2)
void deform_gemm_fb(const float* __restrict__ x, const float* __restrict__ off,
                    const float* __restrict__ wf, float* __restrict__ out) {
    __shared__ float4 s_w[32 * 9];
    __shared__ int4   s_a[32 * 9];
    __shared__ unsigned short sA[2][32 * 32];
    __shared__ unsigned short sB[2][256 * 32];

    const int tid  = threadIdx.x;
    const int lane = tid & 63;
    const int wv   = tid >> 6;
    const int fr   = lane & 15;
    const int fq   = lane >> 4;
    const int bs  = ((blockIdx.x & 7) << 6) | (blockIdx.x >> 3);
    const int b   = bs >> 7;
    const int ho  = (bs >> 1) & 63;
    const int wo0 = (bs & 1) << 5;

    for (int i = tid; i < 32 * 9; i += 256) {
        const int k = i >> 5, p = i & 31, wo = wo0 + p;
        const int kh = k / 3, kw = k - kh * 3;
        const float dy = off[(((b * 18) + 2 * k    ) * 64 + ho) * 64 + wo];
        const float dx = off[(((b * 18) + 2 * k + 1) * 64 + ho) * 64 + wo];
        const float sy = (float)(ho - 1 + kh) + dy;
        const float sx = (float)(wo - 1 + kw) + dx;
        const float y0f = floorf(sy), x0f = floorf(sx);
        const float fy = sy - y0f, fx = sx - x0f;
        const int y0 = (int)y0f, x0 = (int)x0f;
        const int y1 = y0 + 1, x1 = x0 + 1;
        const bool vy0 = (unsigned)y0 < 64u, vy1 = (unsigned)y1 < 64u;
        const bool vx0 = (unsigned)x0 < 64u, vx1 = (unsigned)x1 < 64u;
        const int y0c = min(max(y0, 0), 63), y1c = min(max(y1, 0), 63);
        const int x0c = min(max(x0, 0), 63), x1c = min(max(x1, 0), 63);
        float4 wt;
        wt.x = (1.f - fy) * (1.f - fx) * ((vy0 & vx0) ? 1.f : 0.f);
        wt.y = (1.f - fy) * fx         * ((vy0 & vx1) ? 1.f : 0.f);
        wt.z = fy * (1.f - fx)         * ((vy1 & vx0) ? 1.f : 0.f);
        wt.w = fy * fx                 * ((vy1 & vx1) ? 1.f : 0.f);
        s_w[i] = wt;
        s_a[i] = make_int4((y0c << 6) + x0c, (y0c << 6) + x1c,
                           (y1c << 6) + x0c, (y1c << 6) + x1c);
    }

    f32x4 acc[2][4];
    #pragma unroll
    for (int mf = 0; mf < 2; ++mf)
        #pragma unroll
        for (int nf = 0; nf < 4; ++nf)
            acc[mf][nf] = (f32x4){0.f, 0.f, 0.f, 0.f};

    const float* xb = x + (size_t)b * (256 * 4096);
    const int p  = tid & 31;
    const int rq = tid >> 5;
    const int aw_off = (p << 5) + ((((rq >> 1) ^ ((p >> 1) & 3)) << 3)) + ((rq & 1) << 2);

    int brow[4], bcol[4];
    #pragma unroll
    for (int q = 0; q < 4; ++q) {
        brow[q] = (wv << 6) + (q << 4) + (lane >> 2);
        bcol[q] = ((lane & 3) ^ ((brow[q] >> 1) & 3)) << 3;
    }
    const int bphys = (lane & 3) << 3;

    __syncthreads();

    for (int t = 0; t < NSTEP; ++t) {
        const int cur = t & 1;
        const int r0 = t * RC;
        union { ushort4 u; __bf16 h[4]; } pk;
        #pragma unroll
        for (int j = 0; j < 4; ++j) {
            const int r = r0 + rq * 4 + j;
            const int c = r / 9, k = r - c * 9;
            const float4 wt = s_w[(k << 5) + p];
            const int4 ad = s_a[(k << 5) + p];
            const float* xp = xb + (c << 12);
            pk.h[j] = (__bf16)(wt.x * xp[ad.x] + wt.y * xp[ad.y]
                             + wt.z * xp[ad.z] + wt.w * xp[ad.w]);
        }
        *reinterpret_cast<ushort4*>(&sA[cur][aw_off]) = pk.u;
        #pragma unroll
        for (int q = 0; q < 4; ++q) {
            const float4* s = reinterpret_cast<const float4*>(wf + (size_t)brow[q] * RTOT + r0 + bcol[q]);
            float4 f0 = s[0], f1 = s[1];
            union { uint4 u; __bf16 h[8]; } ub;
            ub.h[0]=(__bf16)f0.x; ub.h[1]=(__bf16)f0.y; ub.h[2]=(__bf16)f0.z; ub.h[3]=(__bf16)f0.w;
            ub.h[4]=(__bf16)f1.x; ub.h[5]=(__bf16)f1.y; ub.h[6]=(__bf16)f1.z; ub.h[7]=(__bf16)f1.w;
            *reinterpret_cast<uint4*>(&sB[cur][(brow[q] << 5) + bphys]) = ub.u;
        }
        __syncthreads();
        bf16x8 af[2], bfr[4];
        #pragma unroll
        for (int mf = 0; mf < 2; ++mf) {
            const int row = mf * 16 + fr;
            af[mf] = *reinterpret_cast<const bf16x8*>(&sA[cur][(row << 5) + ((fq ^ ((row >> 1) & 3)) << 3)]);
        }
        #pragma unroll
        for (int nf = 0; nf < 4; ++nf) {
            const int row = (wv << 6) + nf * 16 + fr;
            bfr[nf] = *reinterpret_cast<const bf16x8*>(&sB[cur][(row << 5) + ((fq ^ ((row >> 1) & 3)) << 3)]);
        }
        #pragma unroll
        for (int mf = 0; mf < 2; ++mf)
            #pragma unroll
            for (int nf = 0; nf < 4; ++nf)
                acc[mf][nf] = __builtin_amdgcn_mfma_f32_16x16x32_bf16(af[mf], bfr[nf], acc[mf][nf], 0, 0, 0);
        __syncthreads();
    }

    float* ob = out + (size_t)b * (256 * 4096) + (ho << 6) + wo0;
    #pragma unroll
    for (int nf = 0; nf < 4; ++nf) {
        const int n = (wv << 6) + nf * 16 + fr;
        #pragma unroll
        for (int mf = 0; mf < 2; ++mf) {
            const int m = mf * 16 + (fq << 2);
            *reinterpret_cast<f32x4*>(&ob[(size_t)n * 4096 + m]) = acc[mf][nf];
        }
    }
}

extern "C" void kernel_launch(void* const* d_in, const int* in_sizes, int n_in,
                              void* d_out, int out_size, void* d_ws, size_t ws_size,
                              hipStream_t stream) {
    const float* x   = (const float*)d_in[0];
    const float* off = (const float*)d_in[1];
    const float* w   = (const float*)d_in[2];
    float* out = (float*)d_out;

    const size_t xh_bytes = (size_t)4 * 64 * 64 * 256 * sizeof(__bf16);   // 8.4 MB
    const size_t wb_bytes = (size_t)256 * RTOT * sizeof(__bf16);          // 1.18 MB
    if (ws_size >= xh_bytes + wb_bytes) {
        __bf16* xh = (__bf16*)d_ws;
        __bf16* wb = (__bf16*)((char*)d_ws + xh_bytes);
        nchw_to_nhwc_bf16<<<dim3(256), dim3(256), 0, stream>>>(x, xh);
        weight_prep<<<dim3(576), dim3(256), 0, stream>>>(w, wb);
        deform_gemm_nhwc<<<dim3(512), dim3(256), 0, stream>>>(off, xh, wb, out);
    } else {
        deform_gemm_fb<<<dim3(512), dim3(256), 0, stream>>>(x, off, w, out);
    }
}